// Round 2
// baseline (657.712 us; speedup 1.0000x reference)
//
#include <hip/hip_runtime.h>
#include <cmath>

#define N_   8
#define C_   64
#define H_   160
#define W_   160
#define HW_  25600
#define HH_  80
#define WH_  80
#define FSZ_ (N_ * C_ * HW_)   // 13,107,200
#define PSZ_ (N_ * HW_)        // 204,800

// -------- K0: reorder conv3x3 weights for NHWC consumption --------
// wqd[((tap*64)+ci)*4 + {0,1,2,3}] = {w1[oc0][ci][tap], w1[oc1][ci][tap],
//                                     w2[oc0][ci][tap], w2[oc1][ci][tap]}
// wqo[tap*64+ci] = out_w[ci][tap]
__global__ __launch_bounds__(256) void reorder_w_kernel(
    const float* __restrict__ w2a, const float* __restrict__ w2b,
    const float* __restrict__ ow, float* __restrict__ wqd,
    float* __restrict__ wqo)
{
    int tid = threadIdx.x;
    for (int i = tid; i < 9 * 64; i += 256) {
        int tap = i / 64, ci = i % 64;
        int src = ci * 9 + tap;
        wqd[i * 4 + 0] = w2a[src];
        wqd[i * 4 + 1] = w2a[576 + src];
        wqd[i * 4 + 2] = w2b[src];
        wqd[i * 4 + 3] = w2b[576 + src];
        wqo[i] = ow[src];
    }
}

// -------- K1: bilinear resize align_corners=True, 80->160 --------
__global__ __launch_bounds__(256) void resize_high_kernel(
    const float* __restrict__ hs, float* __restrict__ high)
{
    int i = blockIdx.x * 256 + threadIdx.x;
    int x  = i % W_;
    int t  = i / W_;
    int y  = t % H_;
    int nc = t / H_;
    float sx = (x * 79.0f) / 159.0f;
    float sy = (y * 79.0f) / 159.0f;
    int ix0 = (int)sx, iy0 = (int)sy;
    float fx = sx - (float)ix0, fy = sy - (float)iy0;
    int ix1 = min(ix0 + 1, WH_ - 1), iy1 = min(iy0 + 1, HH_ - 1);
    const float* p = hs + nc * (HH_ * WH_);
    float v00 = p[iy0 * WH_ + ix0], v01 = p[iy0 * WH_ + ix1];
    float v10 = p[iy1 * WH_ + ix0], v11 = p[iy1 * WH_ + ix1];
    high[i] = (v00 * (1.f - fx) + v01 * fx) * (1.f - fy)
            + (v10 * (1.f - fx) + v11 * fx) * fy;
}

// -------- K1b: resize in_map 80->160 + sigmoid --------
__global__ __launch_bounds__(256) void resize_imap_kernel(
    const float* __restrict__ im, float* __restrict__ imap)
{
    int i = blockIdx.x * 256 + threadIdx.x;
    int x = i % W_;
    int t = i / W_;
    int y = t % H_;
    int n = t / H_;
    float sx = (x * 79.0f) / 159.0f;
    float sy = (y * 79.0f) / 159.0f;
    int ix0 = (int)sx, iy0 = (int)sy;
    float fx = sx - (float)ix0, fy = sy - (float)iy0;
    int ix1 = min(ix0 + 1, WH_ - 1), iy1 = min(iy0 + 1, HH_ - 1);
    const float* p = im + n * (HH_ * WH_);
    float v00 = p[iy0 * WH_ + ix0], v01 = p[iy0 * WH_ + ix1];
    float v10 = p[iy1 * WH_ + ix0], v11 = p[iy1 * WH_ + ix1];
    float v = (v00 * (1.f - fx) + v01 * fx) * (1.f - fy)
            + (v10 * (1.f - fx) + v11 * fx) * fy;
    imap[i] = 1.f / (1.f + expf(-v));
}

// -------- K2: conv1x1 (both branches) + BN -> NHWC outputs --------
__global__ __launch_bounds__(256) void conv1_bn_kernel(
    const float* __restrict__ low, const float* __restrict__ high,
    const float* __restrict__ w1a, const float* __restrict__ w1b,
    const float* __restrict__ s1, const float* __restrict__ b1,
    const float* __restrict__ m1, const float* __restrict__ v1,
    const float* __restrict__ s2, const float* __restrict__ b2,
    const float* __restrict__ m2, const float* __restrict__ v2,
    float* __restrict__ t1n, float* __restrict__ t2n)
{
    __shared__ float cat[128][64];
    int tid = threadIdx.x;
    int pbase = blockIdx.x * 64;

    for (int i = tid; i < 128 * 64; i += 256) {
        int ci = i >> 6, px = i & 63;
        int p = pbase + px;
        int n = p / HW_, rem = p % HW_;
        float v;
        if (ci < 64) v = low [(n * 64 + ci)        * HW_ + rem];
        else         v = high[(n * 64 + (ci - 64)) * HW_ + rem];
        cat[ci][px] = v;
    }
    __syncthreads();

    int lane = tid & 63;
    int wid  = __builtin_amdgcn_readfirstlane(tid >> 6);
    const float* wsel = (wid < 2) ? w1a : w1b;
    int co_off = (wid & 1) * 32;

    float acc[32];
    #pragma unroll
    for (int j = 0; j < 32; ++j) acc[j] = 0.f;

    for (int c4 = 0; c4 < 32; ++c4) {
        float v0  = cat[c4 * 4 + 0][lane];
        float v1x = cat[c4 * 4 + 1][lane];
        float v2x = cat[c4 * 4 + 2][lane];
        float v3  = cat[c4 * 4 + 3][lane];
        #pragma unroll
        for (int j = 0; j < 32; ++j) {
            const float4 wv = *reinterpret_cast<const float4*>(
                wsel + (co_off + j) * 128 + c4 * 4);
            acc[j] = fmaf(v0,  wv.x, acc[j]);
            acc[j] = fmaf(v1x, wv.y, acc[j]);
            acc[j] = fmaf(v2x, wv.z, acc[j]);
            acc[j] = fmaf(v3,  wv.w, acc[j]);
        }
    }

    int p = pbase + lane;
    const float* ss = (wid < 2) ? s1 : s2;
    const float* bb = (wid < 2) ? b1 : b2;
    const float* mm = (wid < 2) ? m1 : m2;
    const float* vv = (wid < 2) ? v1 : v2;
    float* outp = (wid < 2) ? t1n : t2n;
    #pragma unroll
    for (int j4 = 0; j4 < 8; ++j4) {
        float4 st;
        float* sp = &st.x;
        #pragma unroll
        for (int k = 0; k < 4; ++k) {
            int c = co_off + j4 * 4 + k;
            float inv  = ss[c] * rsqrtf(vv[c] + 1e-5f);
            float beta = bb[c] - mm[c] * inv;
            sp[k] = acc[j4 * 4 + k] * inv + beta;
        }
        *reinterpret_cast<float4*>(outp + p * 64 + co_off + j4 * 4) = st;
    }
}

// -------- K3: conv3x3 pad=1, NHWC 64ch -> 2ch, both branches --------
__global__ __launch_bounds__(256) void conv3_d_kernel(
    const float* __restrict__ t1n, const float* __restrict__ t2n,
    const float* __restrict__ wqd, float* __restrict__ d1,
    float* __restrict__ d2)
{
    int p = blockIdx.x * 256 + threadIdx.x;     // pixel over N*HW
    int n = p / HW_, rem = p % HW_;
    int y = rem / W_, x = rem % W_;

    float a10 = 0.f, a11 = 0.f, a20 = 0.f, a21 = 0.f;
    #pragma unroll
    for (int ky = 0; ky < 3; ++ky) {
        int yy = y + ky - 1;
        float ymsk = ((unsigned)yy < (unsigned)H_) ? 1.f : 0.f;
        int yyc = min(max(yy, 0), H_ - 1);
        #pragma unroll
        for (int kx = 0; kx < 3; ++kx) {
            int xx = x + kx - 1;
            float msk = (((unsigned)xx < (unsigned)W_) ? 1.f : 0.f) * ymsk;
            int xxc = min(max(xx, 0), W_ - 1);
            long q = (long)(n * HW_ + yyc * W_ + xxc) * 64;
            const float4* pa = reinterpret_cast<const float4*>(t1n + q);
            const float4* pb = reinterpret_cast<const float4*>(t2n + q);
            const float4* wp = reinterpret_cast<const float4*>(
                wqd + (ky * 3 + kx) * 256);   // 64 ci * 4
            float p10 = 0.f, p11 = 0.f, p20 = 0.f, p21 = 0.f;
            #pragma unroll
            for (int cq = 0; cq < 16; ++cq) {
                float4 va = pa[cq];
                float4 vb = pb[cq];
                float4 w0 = wp[cq * 4 + 0];
                float4 w1 = wp[cq * 4 + 1];
                float4 w2 = wp[cq * 4 + 2];
                float4 w3 = wp[cq * 4 + 3];
                p10 = fmaf(va.x, w0.x, p10); p11 = fmaf(va.x, w0.y, p11);
                p20 = fmaf(vb.x, w0.z, p20); p21 = fmaf(vb.x, w0.w, p21);
                p10 = fmaf(va.y, w1.x, p10); p11 = fmaf(va.y, w1.y, p11);
                p20 = fmaf(vb.y, w1.z, p20); p21 = fmaf(vb.y, w1.w, p21);
                p10 = fmaf(va.z, w2.x, p10); p11 = fmaf(va.z, w2.y, p11);
                p20 = fmaf(vb.z, w2.z, p20); p21 = fmaf(vb.z, w2.w, p21);
                p10 = fmaf(va.w, w3.x, p10); p11 = fmaf(va.w, w3.y, p11);
                p20 = fmaf(vb.w, w3.z, p20); p21 = fmaf(vb.w, w3.w, p21);
            }
            a10 = fmaf(msk, p10, a10); a11 = fmaf(msk, p11, a11);
            a20 = fmaf(msk, p20, a20); a21 = fmaf(msk, p21, a21);
        }
    }
    *reinterpret_cast<float2*>(d1 + p * 2) = make_float2(a10, a11);
    *reinterpret_cast<float2*>(d2 + p * 2) = make_float2(a20, a21);
}

// -------- K4: warp(high,d1)+warp(low,d2) -> f (NCHW to d_out, NHWC to ws) --------
__global__ __launch_bounds__(256) void warp_combine_kernel(
    const float* __restrict__ low, const float* __restrict__ high,
    const float* __restrict__ d1, const float* __restrict__ d2,
    const float* __restrict__ imap, const float* __restrict__ gamma,
    float* __restrict__ f, float* __restrict__ fn)
{
    int p = blockIdx.x * 256 + threadIdx.x;     // pixel over N*HW
    int n = p / HW_, rem = p % HW_;
    int y = rem / W_, x = rem % W_;

    float gx = -1.f + x * (2.f / 159.f);
    float gy = -1.f + y * (2.f / 159.f);

    float2 dv1 = *reinterpret_cast<const float2*>(d1 + p * 2);
    float2 dv2 = *reinterpret_cast<const float2*>(d2 + p * 2);

    int   off1[4], off2[4];
    float wgt1[4], wgt2[4];
    {
        float px = ((gx + dv1.x * (1.f / 160.f)) + 1.f) * 80.f - 0.5f;
        float py = ((gy + dv1.y * (1.f / 160.f)) + 1.f) * 80.f - 0.5f;
        float x0f = floorf(px), y0f = floorf(py);
        float wx1 = px - x0f, wy1 = py - y0f, wx0 = 1.f - wx1, wy0 = 1.f - wy1;
        int x0 = (int)x0f, y0 = (int)y0f;
        float mx0 = ((unsigned)x0       < (unsigned)W_) ? 1.f : 0.f;
        float mx1 = ((unsigned)(x0 + 1) < (unsigned)W_) ? 1.f : 0.f;
        float my0 = ((unsigned)y0       < (unsigned)H_) ? 1.f : 0.f;
        float my1 = ((unsigned)(y0 + 1) < (unsigned)H_) ? 1.f : 0.f;
        int x0c = min(max(x0, 0), W_ - 1), x1c = min(max(x0 + 1, 0), W_ - 1);
        int y0c = min(max(y0, 0), H_ - 1), y1c = min(max(y0 + 1, 0), H_ - 1);
        off1[0] = y0c * W_ + x0c; wgt1[0] = wy0 * wx0 * my0 * mx0;
        off1[1] = y0c * W_ + x1c; wgt1[1] = wy0 * wx1 * my0 * mx1;
        off1[2] = y1c * W_ + x0c; wgt1[2] = wy1 * wx0 * my1 * mx0;
        off1[3] = y1c * W_ + x1c; wgt1[3] = wy1 * wx1 * my1 * mx1;
    }
    {
        float px = ((gx + dv2.x * (1.f / 160.f)) + 1.f) * 80.f - 0.5f;
        float py = ((gy + dv2.y * (1.f / 160.f)) + 1.f) * 80.f - 0.5f;
        float x0f = floorf(px), y0f = floorf(py);
        float wx1 = px - x0f, wy1 = py - y0f, wx0 = 1.f - wx1, wy0 = 1.f - wy1;
        int x0 = (int)x0f, y0 = (int)y0f;
        float mx0 = ((unsigned)x0       < (unsigned)W_) ? 1.f : 0.f;
        float mx1 = ((unsigned)(x0 + 1) < (unsigned)W_) ? 1.f : 0.f;
        float my0 = ((unsigned)y0       < (unsigned)H_) ? 1.f : 0.f;
        float my1 = ((unsigned)(y0 + 1) < (unsigned)H_) ? 1.f : 0.f;
        int x0c = min(max(x0, 0), W_ - 1), x1c = min(max(x0 + 1, 0), W_ - 1);
        int y0c = min(max(y0, 0), H_ - 1), y1c = min(max(y0 + 1, 0), H_ - 1);
        off2[0] = y0c * W_ + x0c; wgt2[0] = wy0 * wx0 * my0 * mx0;
        off2[1] = y0c * W_ + x1c; wgt2[1] = wy0 * wx1 * my0 * mx1;
        off2[2] = y1c * W_ + x0c; wgt2[2] = wy1 * wx0 * my1 * mx0;
        off2[3] = y1c * W_ + x1c; wgt2[3] = wy1 * wx1 * my1 * mx1;
    }

    float s = 1.f + gamma[0] * imap[p];

    const float* hb = high + (long)n * 64 * HW_;
    const float* lb = low  + (long)n * 64 * HW_;
    float* fp = f + (long)n * 64 * HW_ + rem;

    float4 buf;
    float* bp = &buf.x;
    #pragma unroll 4
    for (int c = 0; c < 64; ++c) {
        const float* hc = hb + c * HW_;
        const float* lc = lb + c * HW_;
        float hi = hc[off1[0]] * wgt1[0] + hc[off1[1]] * wgt1[1]
                 + hc[off1[2]] * wgt1[2] + hc[off1[3]] * wgt1[3];
        float lo = lc[off2[0]] * wgt2[0] + lc[off2[1]] * wgt2[1]
                 + lc[off2[2]] * wgt2[2] + lc[off2[3]] * wgt2[3];
        float fv = (hi + lo) * s;
        fp[c * HW_] = fv;
        bp[c & 3] = fv;
        if ((c & 3) == 3)
            *reinterpret_cast<float4*>(fn + (long)p * 64 + (c - 3)) = buf;
    }
}

// -------- K5: conv3x3 pad=1, NHWC 64ch -> 1ch + bias --------
__global__ __launch_bounds__(256) void out_conv_kernel(
    const float* __restrict__ fn, const float* __restrict__ wqo,
    const float* __restrict__ ob, float* __restrict__ o)
{
    int p = blockIdx.x * 256 + threadIdx.x;
    int n = p / HW_, rem = p % HW_;
    int y = rem / W_, x = rem % W_;

    float acc = 0.f;
    #pragma unroll
    for (int ky = 0; ky < 3; ++ky) {
        int yy = y + ky - 1;
        float ymsk = ((unsigned)yy < (unsigned)H_) ? 1.f : 0.f;
        int yyc = min(max(yy, 0), H_ - 1);
        #pragma unroll
        for (int kx = 0; kx < 3; ++kx) {
            int xx = x + kx - 1;
            float msk = (((unsigned)xx < (unsigned)W_) ? 1.f : 0.f) * ymsk;
            int xxc = min(max(xx, 0), W_ - 1);
            long q = (long)(n * HW_ + yyc * W_ + xxc) * 64;
            const float4* pf = reinterpret_cast<const float4*>(fn + q);
            const float4* wp = reinterpret_cast<const float4*>(
                wqo + (ky * 3 + kx) * 64);
            float part = 0.f;
            #pragma unroll
            for (int cq = 0; cq < 16; ++cq) {
                float4 v = pf[cq];
                float4 w = wp[cq];
                part = fmaf(v.x, w.x, part);
                part = fmaf(v.y, w.y, part);
                part = fmaf(v.z, w.z, part);
                part = fmaf(v.w, w.w, part);
            }
            acc = fmaf(msk, part, acc);
        }
    }
    o[p] = acc + ob[0];
}

extern "C" void kernel_launch(void* const* d_in, const int* in_sizes, int n_in,
                              void* d_out, int out_size, void* d_ws, size_t ws_size,
                              hipStream_t stream) {
    const float* low    = (const float*)d_in[0];
    const float* hsin   = (const float*)d_in[1];
    const float* imin   = (const float*)d_in[2];
    const float* dg1_w1 = (const float*)d_in[3];
    const float* dg1_s  = (const float*)d_in[4];
    const float* dg1_b  = (const float*)d_in[5];
    const float* dg1_m  = (const float*)d_in[6];
    const float* dg1_v  = (const float*)d_in[7];
    const float* dg1_w2 = (const float*)d_in[8];
    const float* dg2_w1 = (const float*)d_in[9];
    const float* dg2_s  = (const float*)d_in[10];
    const float* dg2_b  = (const float*)d_in[11];
    const float* dg2_m  = (const float*)d_in[12];
    const float* dg2_v  = (const float*)d_in[13];
    const float* dg2_w2 = (const float*)d_in[14];
    const float* gamma  = (const float*)d_in[15];
    const float* out_w  = (const float*)d_in[16];
    const float* out_b  = (const float*)d_in[17];

    float* ws   = (float*)d_ws;
    float* high = ws;                       // FSZ_ (NCHW)
    float* imap = high + FSZ_;              // PSZ_
    float* t2n  = imap + PSZ_;              // FSZ_ (NHWC; later aliased as fn)
    float* d1   = t2n + FSZ_;               // 2*PSZ_ ([p][2])
    float* d2   = d1 + 2 * PSZ_;            // 2*PSZ_
    float* wqd  = d2 + 2 * PSZ_;            // 2304
    float* wqo  = wqd + 2304;               // 576

    float* fout = (float*)d_out;            // FSZ_ (output 0, NCHW)
    float* t1n  = fout;                     // staged NHWC in d_out; dead before K4
    float* oout = fout + FSZ_;              // PSZ_ (output 1)
    float* fn   = t2n;                      // NHWC f, aliases dead t2n

    reorder_w_kernel<<<1, 256, 0, stream>>>(dg1_w2, dg2_w2, out_w, wqd, wqo);
    resize_high_kernel<<<FSZ_ / 256, 256, 0, stream>>>(hsin, high);
    resize_imap_kernel<<<PSZ_ / 256, 256, 0, stream>>>(imin, imap);
    conv1_bn_kernel<<<PSZ_ / 64, 256, 0, stream>>>(
        low, high, dg1_w1, dg2_w1,
        dg1_s, dg1_b, dg1_m, dg1_v,
        dg2_s, dg2_b, dg2_m, dg2_v, t1n, t2n);
    conv3_d_kernel<<<PSZ_ / 256, 256, 0, stream>>>(t1n, t2n, wqd, d1, d2);
    warp_combine_kernel<<<PSZ_ / 256, 256, 0, stream>>>(
        low, high, d1, d2, imap, gamma, fout, fn);
    out_conv_kernel<<<PSZ_ / 256, 256, 0, stream>>>(fn, wqo, out_b, oout);
}

// Round 3
// 391.142 us; speedup vs baseline: 1.6815x; 1.6815x over previous
//
#include <hip/hip_runtime.h>
#include <cmath>

#define N_   8
#define C_   64
#define H_   160
#define W_   160
#define HW_  25600
#define HH_  80
#define WH_  80
#define FSZ_ (N_ * C_ * HW_)   // 13,107,200
#define PSZ_ (N_ * HW_)        // 204,800

typedef unsigned short ushort8v __attribute__((ext_vector_type(8)));

__device__ __forceinline__ float bf2f(unsigned short u) {
    return __uint_as_float(((unsigned)u) << 16);
}
__device__ __forceinline__ unsigned short f2bf(float f) {
    unsigned u = __float_as_uint(f);
    u += 0x7FFF + ((u >> 16) & 1);          // RNE
    return (unsigned short)(u >> 16);
}

// -------- K0: reorder conv3x3 weights --------
// wqd[((br*9+tap)*64+ci)*2+oc] = w_br[oc][ci][tap]   (d-branch convs)
// wqo[tap*64+ci]               = out_w[0][ci][tap]
__global__ __launch_bounds__(256) void reorder_w_kernel(
    const float* __restrict__ w2a, const float* __restrict__ w2b,
    const float* __restrict__ ow, float* __restrict__ wqd,
    float* __restrict__ wqo)
{
    int tid = threadIdx.x;
    for (int i = tid; i < 2304; i += 256) {
        int oc  = i & 1;
        int ci  = (i >> 1) & 63;
        int tap = (i >> 7) % 9;
        int br  = i / 1152;
        const float* src = br ? w2b : w2a;
        wqd[i] = src[oc * 576 + ci * 9 + tap];
    }
    for (int i = tid; i < 576; i += 256) {
        int tap = i / 64, ci = i % 64;
        wqo[i] = ow[ci * 9 + tap];
    }
}

// -------- K1: bilinear resize align_corners=True, 80->160 --------
__global__ __launch_bounds__(256) void resize_high_kernel(
    const float* __restrict__ hs, float* __restrict__ high)
{
    int i = blockIdx.x * 256 + threadIdx.x;
    int x  = i % W_;
    int t  = i / W_;
    int y  = t % H_;
    int nc = t / H_;
    float sx = (x * 79.0f) / 159.0f;
    float sy = (y * 79.0f) / 159.0f;
    int ix0 = (int)sx, iy0 = (int)sy;
    float fx = sx - (float)ix0, fy = sy - (float)iy0;
    int ix1 = min(ix0 + 1, WH_ - 1), iy1 = min(iy0 + 1, HH_ - 1);
    const float* p = hs + nc * (HH_ * WH_);
    float v00 = p[iy0 * WH_ + ix0], v01 = p[iy0 * WH_ + ix1];
    float v10 = p[iy1 * WH_ + ix0], v11 = p[iy1 * WH_ + ix1];
    high[i] = (v00 * (1.f - fx) + v01 * fx) * (1.f - fy)
            + (v10 * (1.f - fx) + v11 * fx) * fy;
}

// -------- K1b: resize in_map 80->160 + sigmoid --------
__global__ __launch_bounds__(256) void resize_imap_kernel(
    const float* __restrict__ im, float* __restrict__ imap)
{
    int i = blockIdx.x * 256 + threadIdx.x;
    int x = i % W_;
    int t = i / W_;
    int y = t % H_;
    int n = t / H_;
    float sx = (x * 79.0f) / 159.0f;
    float sy = (y * 79.0f) / 159.0f;
    int ix0 = (int)sx, iy0 = (int)sy;
    float fx = sx - (float)ix0, fy = sy - (float)iy0;
    int ix1 = min(ix0 + 1, WH_ - 1), iy1 = min(iy0 + 1, HH_ - 1);
    const float* p = im + n * (HH_ * WH_);
    float v00 = p[iy0 * WH_ + ix0], v01 = p[iy0 * WH_ + ix1];
    float v10 = p[iy1 * WH_ + ix0], v11 = p[iy1 * WH_ + ix1];
    float v = (v00 * (1.f - fx) + v01 * fx) * (1.f - fy)
            + (v10 * (1.f - fx) + v11 * fx) * fy;
    imap[i] = 1.f / (1.f + expf(-v));
}

// -------- K2: conv1x1 (both branches) + BN -> bf16 NHWC --------
__global__ __launch_bounds__(256) void conv1_bn_kernel(
    const float* __restrict__ low, const float* __restrict__ high,
    const float* __restrict__ w1a, const float* __restrict__ w1b,
    const float* __restrict__ s1, const float* __restrict__ b1,
    const float* __restrict__ m1, const float* __restrict__ v1,
    const float* __restrict__ s2, const float* __restrict__ b2,
    const float* __restrict__ m2, const float* __restrict__ v2,
    unsigned short* __restrict__ t1b, unsigned short* __restrict__ t2b)
{
    __shared__ float cat[128][64];
    int tid = threadIdx.x;
    int pbase = blockIdx.x * 64;
    int n = pbase / HW_, rem_base = pbase % HW_;   // 64 pixels share n (HW_%64==0)

    for (int i = tid; i < 2048; i += 256) {        // 128 ch * 16 quads
        int ci = i >> 4, q = i & 15;
        const float* base = (ci < 64) ? low : high;
        float4 v = *reinterpret_cast<const float4*>(
            base + (long)(n * 64 + (ci & 63)) * HW_ + rem_base + q * 4);
        *reinterpret_cast<float4*>(&cat[ci][q * 4]) = v;
    }
    __syncthreads();

    int lane = tid & 63;
    int wid  = __builtin_amdgcn_readfirstlane(tid >> 6);
    const float* wsel = (wid < 2) ? w1a : w1b;
    int co_off = (wid & 1) * 32;

    float acc[32];
    #pragma unroll
    for (int j = 0; j < 32; ++j) acc[j] = 0.f;

    for (int c4 = 0; c4 < 32; ++c4) {
        float v0  = cat[c4 * 4 + 0][lane];
        float v1x = cat[c4 * 4 + 1][lane];
        float v2x = cat[c4 * 4 + 2][lane];
        float v3  = cat[c4 * 4 + 3][lane];
        #pragma unroll
        for (int j = 0; j < 32; ++j) {
            const float4 wv = *reinterpret_cast<const float4*>(
                wsel + (co_off + j) * 128 + c4 * 4);
            acc[j] = fmaf(v0,  wv.x, acc[j]);
            acc[j] = fmaf(v1x, wv.y, acc[j]);
            acc[j] = fmaf(v2x, wv.z, acc[j]);
            acc[j] = fmaf(v3,  wv.w, acc[j]);
        }
    }

    int p = pbase + lane;
    const float* ss = (wid < 2) ? s1 : s2;
    const float* bb = (wid < 2) ? b1 : b2;
    const float* mm = (wid < 2) ? m1 : m2;
    const float* vv = (wid < 2) ? v1 : v2;
    unsigned short* outp = (wid < 2) ? t1b : t2b;
    #pragma unroll
    for (int j4 = 0; j4 < 8; ++j4) {
        ushort4 st;
        unsigned short* sp = &st.x;
        #pragma unroll
        for (int k = 0; k < 4; ++k) {
            int c = co_off + j4 * 4 + k;
            float inv  = ss[c] * rsqrtf(vv[c] + 1e-5f);
            float beta = bb[c] - mm[c] * inv;
            sp[k] = f2bf(acc[j4 * 4 + k] * inv + beta);
        }
        *reinterpret_cast<ushort4*>(outp + (long)p * 64 + co_off + j4 * 4) = st;
    }
}

// -------- K3: conv3x3 pad=1, bf16 NHWC 64->2, LDS-tiled, one branch/block ----
// grid = 2 * 8 * 100; tile 16x16, halo 18x18
__global__ __launch_bounds__(256) void conv3_d_tiled(
    const unsigned short* __restrict__ t1b, const unsigned short* __restrict__ t2b,
    const float* __restrict__ wqd, float* __restrict__ d1, float* __restrict__ d2)
{
    __shared__ unsigned char lds[324 * 128];     // 41,472 B, swizzled
    int b  = blockIdx.x;
    int br = b / 800;
    int r  = b % 800;
    int n  = r / 100;
    int t  = r % 100;
    int ty = t / 10, tx = t % 10;
    int y0 = ty * 16 - 1, x0 = tx * 16 - 1;
    int tid = threadIdx.x;

    const unsigned short* src = br ? t2b : t1b;
    float* dst = br ? d2 : d1;

    for (int i = tid; i < 324 * 8; i += 256) {
        int pix = i >> 3, qq = i & 7;
        int py = pix / 18, px = pix % 18;
        int yy = min(max(y0 + py, 0), H_ - 1);
        int xx = min(max(x0 + px, 0), W_ - 1);
        ushort8v v = *reinterpret_cast<const ushort8v*>(
            src + ((long)(n * HW_ + yy * W_ + xx)) * 64 + qq * 8);
        *reinterpret_cast<ushort8v*>(
            lds + ((pix * 128 + qq * 16) ^ ((pix & 7) << 4))) = v;
    }
    __syncthreads();

    int oy = tid >> 4, ox = tid & 15;
    int gy = ty * 16 + oy, gx = tx * 16 + ox;
    const float* wbase = wqd + br * 1152;

    float a0 = 0.f, a1 = 0.f;
    #pragma unroll
    for (int ky = 0; ky < 3; ++ky) {
        int yy = gy + ky - 1;
        float ym = ((unsigned)yy < (unsigned)H_) ? 1.f : 0.f;
        #pragma unroll
        for (int kx = 0; kx < 3; ++kx) {
            int xx = gx + kx - 1;
            float m = (((unsigned)xx < (unsigned)W_) ? 1.f : 0.f) * ym;
            int tp = (oy + ky) * 18 + (ox + kx);
            const float* wp = wbase + (ky * 3 + kx) * 128;   // uniform -> SGPR
            float p0 = 0.f, p1 = 0.f;
            #pragma unroll
            for (int qq = 0; qq < 8; ++qq) {
                ushort8v v = *reinterpret_cast<const ushort8v*>(
                    lds + ((tp * 128 + qq * 16) ^ ((tp & 7) << 4)));
                #pragma unroll
                for (int k = 0; k < 8; ++k) {
                    float fv = bf2f(v[k]);
                    p0 = fmaf(fv, wp[(qq * 8 + k) * 2 + 0], p0);
                    p1 = fmaf(fv, wp[(qq * 8 + k) * 2 + 1], p1);
                }
            }
            a0 = fmaf(m, p0, a0);
            a1 = fmaf(m, p1, a1);
        }
    }
    int p = n * HW_ + gy * W_ + gx;
    *reinterpret_cast<float2*>(dst + (long)p * 2) = make_float2(a0, a1);
}

// -------- K4: warp(high,d1)+warp(low,d2) -> f (fp32 NCHW) + fnb (bf16 NHWC) --
__global__ __launch_bounds__(256) void warp_combine_kernel(
    const float* __restrict__ low, const float* __restrict__ high,
    const float* __restrict__ d1, const float* __restrict__ d2,
    const float* __restrict__ imap, const float* __restrict__ gamma,
    float* __restrict__ f, unsigned short* __restrict__ fnb)
{
    int p = blockIdx.x * 256 + threadIdx.x;
    int n = p / HW_, rem = p % HW_;
    int y = rem / W_, x = rem % W_;

    float gx = -1.f + x * (2.f / 159.f);
    float gy = -1.f + y * (2.f / 159.f);

    float2 dv1 = *reinterpret_cast<const float2*>(d1 + (long)p * 2);
    float2 dv2 = *reinterpret_cast<const float2*>(d2 + (long)p * 2);

    int   off1[4], off2[4];
    float wgt1[4], wgt2[4];
    {
        float px = ((gx + dv1.x * (1.f / 160.f)) + 1.f) * 80.f - 0.5f;
        float py = ((gy + dv1.y * (1.f / 160.f)) + 1.f) * 80.f - 0.5f;
        float x0f = floorf(px), y0f = floorf(py);
        float wx1 = px - x0f, wy1 = py - y0f, wx0 = 1.f - wx1, wy0 = 1.f - wy1;
        int x0 = (int)x0f, y0 = (int)y0f;
        float mx0 = ((unsigned)x0       < (unsigned)W_) ? 1.f : 0.f;
        float mx1 = ((unsigned)(x0 + 1) < (unsigned)W_) ? 1.f : 0.f;
        float my0 = ((unsigned)y0       < (unsigned)H_) ? 1.f : 0.f;
        float my1 = ((unsigned)(y0 + 1) < (unsigned)H_) ? 1.f : 0.f;
        int x0c = min(max(x0, 0), W_ - 1), x1c = min(max(x0 + 1, 0), W_ - 1);
        int y0c = min(max(y0, 0), H_ - 1), y1c = min(max(y0 + 1, 0), H_ - 1);
        off1[0] = y0c * W_ + x0c; wgt1[0] = wy0 * wx0 * my0 * mx0;
        off1[1] = y0c * W_ + x1c; wgt1[1] = wy0 * wx1 * my0 * mx1;
        off1[2] = y1c * W_ + x0c; wgt1[2] = wy1 * wx0 * my1 * mx0;
        off1[3] = y1c * W_ + x1c; wgt1[3] = wy1 * wx1 * my1 * mx1;
    }
    {
        float px = ((gx + dv2.x * (1.f / 160.f)) + 1.f) * 80.f - 0.5f;
        float py = ((gy + dv2.y * (1.f / 160.f)) + 1.f) * 80.f - 0.5f;
        float x0f = floorf(px), y0f = floorf(py);
        float wx1 = px - x0f, wy1 = py - y0f, wx0 = 1.f - wx1, wy0 = 1.f - wy1;
        int x0 = (int)x0f, y0 = (int)y0f;
        float mx0 = ((unsigned)x0       < (unsigned)W_) ? 1.f : 0.f;
        float mx1 = ((unsigned)(x0 + 1) < (unsigned)W_) ? 1.f : 0.f;
        float my0 = ((unsigned)y0       < (unsigned)H_) ? 1.f : 0.f;
        float my1 = ((unsigned)(y0 + 1) < (unsigned)H_) ? 1.f : 0.f;
        int x0c = min(max(x0, 0), W_ - 1), x1c = min(max(x0 + 1, 0), W_ - 1);
        int y0c = min(max(y0, 0), H_ - 1), y1c = min(max(y0 + 1, 0), H_ - 1);
        off2[0] = y0c * W_ + x0c; wgt2[0] = wy0 * wx0 * my0 * mx0;
        off2[1] = y0c * W_ + x1c; wgt2[1] = wy0 * wx1 * my0 * mx1;
        off2[2] = y1c * W_ + x0c; wgt2[2] = wy1 * wx0 * my1 * mx0;
        off2[3] = y1c * W_ + x1c; wgt2[3] = wy1 * wx1 * my1 * mx1;
    }

    float s = 1.f + gamma[0] * imap[p];

    const float* hb = high + (long)n * 64 * HW_;
    const float* lb = low  + (long)n * 64 * HW_;
    float* fp = f + (long)n * 64 * HW_ + rem;

    ushort4 buf;
    unsigned short* bp = &buf.x;
    #pragma unroll 4
    for (int c = 0; c < 64; ++c) {
        const float* hc = hb + c * HW_;
        const float* lc = lb + c * HW_;
        float hi = hc[off1[0]] * wgt1[0] + hc[off1[1]] * wgt1[1]
                 + hc[off1[2]] * wgt1[2] + hc[off1[3]] * wgt1[3];
        float lo = lc[off2[0]] * wgt2[0] + lc[off2[1]] * wgt2[1]
                 + lc[off2[2]] * wgt2[2] + lc[off2[3]] * wgt2[3];
        float fv = (hi + lo) * s;
        fp[c * HW_] = fv;
        bp[c & 3] = f2bf(fv);
        if ((c & 3) == 3)
            *reinterpret_cast<ushort4*>(fnb + (long)p * 64 + (c - 3)) = buf;
    }
}

// -------- K5: conv3x3 pad=1, bf16 NHWC 64->1 + bias, LDS-tiled --------
__global__ __launch_bounds__(256) void out_conv_tiled(
    const unsigned short* __restrict__ fnb, const float* __restrict__ wqo,
    const float* __restrict__ ob, float* __restrict__ o)
{
    __shared__ unsigned char lds[324 * 128];
    int b  = blockIdx.x;                   // 0..799
    int n  = b / 100;
    int t  = b % 100;
    int ty = t / 10, tx = t % 10;
    int y0 = ty * 16 - 1, x0 = tx * 16 - 1;
    int tid = threadIdx.x;

    for (int i = tid; i < 324 * 8; i += 256) {
        int pix = i >> 3, qq = i & 7;
        int py = pix / 18, px = pix % 18;
        int yy = min(max(y0 + py, 0), H_ - 1);
        int xx = min(max(x0 + px, 0), W_ - 1);
        ushort8v v = *reinterpret_cast<const ushort8v*>(
            fnb + ((long)(n * HW_ + yy * W_ + xx)) * 64 + qq * 8);
        *reinterpret_cast<ushort8v*>(
            lds + ((pix * 128 + qq * 16) ^ ((pix & 7) << 4))) = v;
    }
    __syncthreads();

    int oy = tid >> 4, ox = tid & 15;
    int gy = ty * 16 + oy, gx = tx * 16 + ox;

    float acc = 0.f;
    #pragma unroll
    for (int ky = 0; ky < 3; ++ky) {
        int yy = gy + ky - 1;
        float ym = ((unsigned)yy < (unsigned)H_) ? 1.f : 0.f;
        #pragma unroll
        for (int kx = 0; kx < 3; ++kx) {
            int xx = gx + kx - 1;
            float m = (((unsigned)xx < (unsigned)W_) ? 1.f : 0.f) * ym;
            int tp = (oy + ky) * 18 + (ox + kx);
            const float* wp = wqo + (ky * 3 + kx) * 64;      // uniform
            float part = 0.f;
            #pragma unroll
            for (int qq = 0; qq < 8; ++qq) {
                ushort8v v = *reinterpret_cast<const ushort8v*>(
                    lds + ((tp * 128 + qq * 16) ^ ((tp & 7) << 4)));
                #pragma unroll
                for (int k = 0; k < 8; ++k)
                    part = fmaf(bf2f(v[k]), wp[qq * 8 + k], part);
            }
            acc = fmaf(m, part, acc);
        }
    }
    o[n * HW_ + gy * W_ + gx] = acc + ob[0];
}

extern "C" void kernel_launch(void* const* d_in, const int* in_sizes, int n_in,
                              void* d_out, int out_size, void* d_ws, size_t ws_size,
                              hipStream_t stream) {
    const float* low    = (const float*)d_in[0];
    const float* hsin   = (const float*)d_in[1];
    const float* imin   = (const float*)d_in[2];
    const float* dg1_w1 = (const float*)d_in[3];
    const float* dg1_s  = (const float*)d_in[4];
    const float* dg1_b  = (const float*)d_in[5];
    const float* dg1_m  = (const float*)d_in[6];
    const float* dg1_v  = (const float*)d_in[7];
    const float* dg1_w2 = (const float*)d_in[8];
    const float* dg2_w1 = (const float*)d_in[9];
    const float* dg2_s  = (const float*)d_in[10];
    const float* dg2_b  = (const float*)d_in[11];
    const float* dg2_m  = (const float*)d_in[12];
    const float* dg2_v  = (const float*)d_in[13];
    const float* dg2_w2 = (const float*)d_in[14];
    const float* gamma  = (const float*)d_in[15];
    const float* out_w  = (const float*)d_in[16];
    const float* out_b  = (const float*)d_in[17];

    float* ws   = (float*)d_ws;
    float* high = ws;                           // FSZ_ fp32 NCHW
    float* imap = high + FSZ_;                  // PSZ_
    float* d1   = imap + PSZ_;                  // 2*PSZ_
    float* d2   = d1 + 2 * PSZ_;                // 2*PSZ_
    float* wqd  = d2 + 2 * PSZ_;                // 2304
    float* wqo  = wqd + 2304;                   // 576
    unsigned short* t1b = (unsigned short*)(wqo + 576);   // FSZ_ bf16 NHWC
    unsigned short* t2b = t1b + FSZ_;                     // FSZ_ bf16 NHWC
    unsigned short* fnb = t1b;                  // aliases t1b (dead after conv3)

    float* fout = (float*)d_out;                // FSZ_ (output 0, NCHW)
    float* oout = fout + FSZ_;                  // PSZ_ (output 1)

    reorder_w_kernel<<<1, 256, 0, stream>>>(dg1_w2, dg2_w2, out_w, wqd, wqo);
    resize_high_kernel<<<FSZ_ / 256, 256, 0, stream>>>(hsin, high);
    resize_imap_kernel<<<PSZ_ / 256, 256, 0, stream>>>(imin, imap);
    conv1_bn_kernel<<<PSZ_ / 64, 256, 0, stream>>>(
        low, high, dg1_w1, dg2_w1,
        dg1_s, dg1_b, dg1_m, dg1_v,
        dg2_s, dg2_b, dg2_m, dg2_v, t1b, t2b);
    conv3_d_tiled<<<1600, 256, 0, stream>>>(t1b, t2b, wqd, d1, d2);
    warp_combine_kernel<<<PSZ_ / 256, 256, 0, stream>>>(
        low, high, d1, d2, imap, gamma, fout, fnb);
    out_conv_tiled<<<800, 256, 0, stream>>>(fnb, wqo, out_b, oout);
}

// Round 4
// 272.632 us; speedup vs baseline: 2.4125x; 1.4347x over previous
//
#include <hip/hip_runtime.h>
#include <cmath>

#define N_   8
#define C_   64
#define H_   160
#define W_   160
#define HW_  25600
#define HH_  80
#define WH_  80
#define FSZ_ (N_ * C_ * HW_)   // 13,107,200
#define PSZ_ (N_ * HW_)        // 204,800

typedef unsigned short ushort8v __attribute__((ext_vector_type(8)));
typedef short          bf16x8  __attribute__((ext_vector_type(8)));
typedef float          f32x4   __attribute__((ext_vector_type(4)));

__device__ __forceinline__ float bf2f(unsigned short u) {
    return __uint_as_float(((unsigned)u) << 16);
}
__device__ __forceinline__ unsigned short f2bf(float f) {
    unsigned u = __float_as_uint(f);
    u += 0x7FFF + ((u >> 16) & 1);          // RNE
    return (unsigned short)(u >> 16);
}

// -------- K0: weight prep --------
// wqb[((kb*128+co)*4+quad)*8+j] = bf16( w1[co][k] * inv[co] ),  k=kb*32+quad*8+j
// beta[co] = b[co] - m[co]*inv[co]
// wqd[((br*9+tap)*64+ci)*2+oc] = w2_br[oc][ci][tap]
// wqo[tap*64+ci] = out_w[0][ci][tap]
__global__ __launch_bounds__(256) void reorder_w_kernel(
    const float* __restrict__ w1a, const float* __restrict__ w1b,
    const float* __restrict__ s1, const float* __restrict__ b1,
    const float* __restrict__ m1, const float* __restrict__ v1,
    const float* __restrict__ s2, const float* __restrict__ b2,
    const float* __restrict__ m2, const float* __restrict__ v2,
    const float* __restrict__ w2a, const float* __restrict__ w2b,
    const float* __restrict__ ow,
    unsigned short* __restrict__ wqb, float* __restrict__ beta,
    float* __restrict__ wqd, float* __restrict__ wqo)
{
    int tid = threadIdx.x;
    for (int i = tid; i < 16384; i += 256) {
        int j    = i & 7;
        int quad = (i >> 3) & 3;
        int co   = (i >> 5) & 127;
        int kb   = i >> 12;
        int k    = kb * 32 + quad * 8 + j;
        float wt, inv;
        if (co < 64) {
            wt  = w1a[co * 128 + k];
            inv = s1[co] * rsqrtf(v1[co] + 1e-5f);
        } else {
            wt  = w1b[(co - 64) * 128 + k];
            inv = s2[co - 64] * rsqrtf(v2[co - 64] + 1e-5f);
        }
        wqb[i] = f2bf(wt * inv);
    }
    for (int co = tid; co < 128; co += 256) {
        float inv, be;
        if (co < 64) {
            inv = s1[co] * rsqrtf(v1[co] + 1e-5f);
            be  = b1[co] - m1[co] * inv;
        } else {
            inv = s2[co - 64] * rsqrtf(v2[co - 64] + 1e-5f);
            be  = b2[co - 64] - m2[co - 64] * inv;
        }
        beta[co] = be;
    }
    for (int i = tid; i < 2304; i += 256) {
        int oc  = i & 1;
        int ci  = (i >> 1) & 63;
        int tap = (i >> 7) % 9;
        int br  = i / 1152;
        const float* src = br ? w2b : w2a;
        wqd[i] = src[oc * 576 + ci * 9 + tap];
    }
    for (int i = tid; i < 576; i += 256) {
        int tap = i / 64, ci = i % 64;
        wqo[i] = ow[ci * 9 + tap];
    }
}

// -------- K1: bilinear resize align_corners=True, 80->160 --------
__global__ __launch_bounds__(256) void resize_high_kernel(
    const float* __restrict__ hs, float* __restrict__ high)
{
    int i = blockIdx.x * 256 + threadIdx.x;
    int x  = i % W_;
    int t  = i / W_;
    int y  = t % H_;
    int nc = t / H_;
    float sx = (x * 79.0f) / 159.0f;
    float sy = (y * 79.0f) / 159.0f;
    int ix0 = (int)sx, iy0 = (int)sy;
    float fx = sx - (float)ix0, fy = sy - (float)iy0;
    int ix1 = min(ix0 + 1, WH_ - 1), iy1 = min(iy0 + 1, HH_ - 1);
    const float* p = hs + nc * (HH_ * WH_);
    float v00 = p[iy0 * WH_ + ix0], v01 = p[iy0 * WH_ + ix1];
    float v10 = p[iy1 * WH_ + ix0], v11 = p[iy1 * WH_ + ix1];
    high[i] = (v00 * (1.f - fx) + v01 * fx) * (1.f - fy)
            + (v10 * (1.f - fx) + v11 * fx) * fy;
}

// -------- K1b: resize in_map 80->160 + sigmoid --------
__global__ __launch_bounds__(256) void resize_imap_kernel(
    const float* __restrict__ im, float* __restrict__ imap)
{
    int i = blockIdx.x * 256 + threadIdx.x;
    int x = i % W_;
    int t = i / W_;
    int y = t % H_;
    int n = t / H_;
    float sx = (x * 79.0f) / 159.0f;
    float sy = (y * 79.0f) / 159.0f;
    int ix0 = (int)sx, iy0 = (int)sy;
    float fx = sx - (float)ix0, fy = sy - (float)iy0;
    int ix1 = min(ix0 + 1, WH_ - 1), iy1 = min(iy0 + 1, HH_ - 1);
    const float* p = im + n * (HH_ * WH_);
    float v00 = p[iy0 * WH_ + ix0], v01 = p[iy0 * WH_ + ix1];
    float v10 = p[iy1 * WH_ + ix0], v11 = p[iy1 * WH_ + ix1];
    float v = (v00 * (1.f - fx) + v01 * fx) * (1.f - fy)
            + (v10 * (1.f - fx) + v11 * fx) * fy;
    imap[i] = 1.f / (1.f + expf(-v));
}

// -------- K2: conv1x1 + BN via bf16 MFMA -> bf16 NHWC --------
// block = 256 (4 waves); block tile = 64 px x 128 co, K=128.
// wave w owns px rows w*16..w*16+15.  A: global->reg direct; B: L1-resident table.
__global__ __launch_bounds__(256) void conv1_mfma_kernel(
    const float* __restrict__ low, const float* __restrict__ high,
    const unsigned short* __restrict__ wqb, const float* __restrict__ beta,
    unsigned short* __restrict__ t1b, unsigned short* __restrict__ t2b)
{
    int tid  = threadIdx.x;
    int lane = tid & 63;
    int wv   = tid >> 6;
    int r16  = lane & 15;
    int quad = lane >> 4;

    int pbase = blockIdx.x * 64;
    int n   = pbase / HW_;
    int rem = pbase % HW_;                 // HW_ % 64 == 0 -> block within one n
    int apx = rem + wv * 16 + r16;         // A-row pixel offset in image

    // ---- A fragments: 4 kblk x 8 consecutive ci at fixed px ----
    bf16x8 afrag[4];
    #pragma unroll
    for (int kb = 0; kb < 4; ++kb) {
        const float* src = (kb < 2) ? low : high;
        int cbase = (kb & 1) * 32 + quad * 8;     // ci within 64-ch tensor
        float v[8];
        #pragma unroll
        for (int j = 0; j < 8; ++j)
            v[j] = src[((long)(n * 64 + cbase + j)) * HW_ + apx];
        bf16x8 a;
        #pragma unroll
        for (int j = 0; j < 8; ++j)
            a[j] = (short)f2bf(v[j]);
        afrag[kb] = a;
    }

    // ---- MFMA: 8 co-tiles x 4 kblk ----
    f32x4 acc[8];
    #pragma unroll
    for (int ct = 0; ct < 8; ++ct) acc[ct] = (f32x4){0.f, 0.f, 0.f, 0.f};

    #pragma unroll
    for (int kb = 0; kb < 4; ++kb) {
        #pragma unroll
        for (int ct = 0; ct < 8; ++ct) {
            int co = ct * 16 + r16;
            bf16x8 b = *reinterpret_cast<const bf16x8*>(
                wqb + (((kb * 128 + co) * 4 + quad) << 3));
            acc[ct] = __builtin_amdgcn_mfma_f32_16x16x32_bf16(
                afrag[kb], b, acc[ct], 0, 0, 0);
        }
    }

    // ---- epilogue: + beta, f2bf, store NHWC ----
    #pragma unroll
    for (int ct = 0; ct < 8; ++ct) {
        int co = ct * 16 + r16;
        float be = beta[co];
        unsigned short* outp = (ct < 4) ? t1b : t2b;
        int cc = co & 63;
        #pragma unroll
        for (int r = 0; r < 4; ++r) {
            int px = pbase + wv * 16 + quad * 4 + r;   // D row = (lane>>4)*4+r
            outp[(long)px * 64 + cc] = f2bf(acc[ct][r] + be);
        }
    }
}

// -------- K3: conv3x3 pad=1, bf16 NHWC 64->2, LDS-tiled, one branch/block ----
__global__ __launch_bounds__(256) void conv3_d_tiled(
    const unsigned short* __restrict__ t1b, const unsigned short* __restrict__ t2b,
    const float* __restrict__ wqd, float* __restrict__ d1, float* __restrict__ d2)
{
    __shared__ unsigned char lds[324 * 128];     // 41,472 B, swizzled
    int b  = blockIdx.x;
    int br = b / 800;
    int r  = b % 800;
    int n  = r / 100;
    int t  = r % 100;
    int ty = t / 10, tx = t % 10;
    int y0 = ty * 16 - 1, x0 = tx * 16 - 1;
    int tid = threadIdx.x;

    const unsigned short* src = br ? t2b : t1b;
    float* dst = br ? d2 : d1;

    for (int i = tid; i < 324 * 8; i += 256) {
        int pix = i >> 3, qq = i & 7;
        int py = pix / 18, px = pix % 18;
        int yy = min(max(y0 + py, 0), H_ - 1);
        int xx = min(max(x0 + px, 0), W_ - 1);
        ushort8v v = *reinterpret_cast<const ushort8v*>(
            src + ((long)(n * HW_ + yy * W_ + xx)) * 64 + qq * 8);
        *reinterpret_cast<ushort8v*>(
            lds + ((pix * 128 + qq * 16) ^ ((pix & 7) << 4))) = v;
    }
    __syncthreads();

    int oy = tid >> 4, ox = tid & 15;
    int gy = ty * 16 + oy, gx = tx * 16 + ox;
    const float* wbase = wqd + br * 1152;

    float a0 = 0.f, a1 = 0.f;
    #pragma unroll
    for (int ky = 0; ky < 3; ++ky) {
        int yy = gy + ky - 1;
        float ym = ((unsigned)yy < (unsigned)H_) ? 1.f : 0.f;
        #pragma unroll
        for (int kx = 0; kx < 3; ++kx) {
            int xx = gx + kx - 1;
            float m = (((unsigned)xx < (unsigned)W_) ? 1.f : 0.f) * ym;
            int tp = (oy + ky) * 18 + (ox + kx);
            const float* wp = wbase + (ky * 3 + kx) * 128;   // uniform -> SGPR
            float p0 = 0.f, p1 = 0.f;
            #pragma unroll
            for (int qq = 0; qq < 8; ++qq) {
                ushort8v v = *reinterpret_cast<const ushort8v*>(
                    lds + ((tp * 128 + qq * 16) ^ ((tp & 7) << 4)));
                #pragma unroll
                for (int k = 0; k < 8; ++k) {
                    float fv = bf2f(v[k]);
                    p0 = fmaf(fv, wp[(qq * 8 + k) * 2 + 0], p0);
                    p1 = fmaf(fv, wp[(qq * 8 + k) * 2 + 1], p1);
                }
            }
            a0 = fmaf(m, p0, a0);
            a1 = fmaf(m, p1, a1);
        }
    }
    int p = n * HW_ + gy * W_ + gx;
    *reinterpret_cast<float2*>(dst + (long)p * 2) = make_float2(a0, a1);
}

// -------- K4: warp(high,d1)+warp(low,d2) -> f (fp32 NCHW) + fnb (bf16 NHWC) --
__global__ __launch_bounds__(256) void warp_combine_kernel(
    const float* __restrict__ low, const float* __restrict__ high,
    const float* __restrict__ d1, const float* __restrict__ d2,
    const float* __restrict__ imap, const float* __restrict__ gamma,
    float* __restrict__ f, unsigned short* __restrict__ fnb)
{
    int p = blockIdx.x * 256 + threadIdx.x;
    int n = p / HW_, rem = p % HW_;
    int y = rem / W_, x = rem % W_;

    float gx = -1.f + x * (2.f / 159.f);
    float gy = -1.f + y * (2.f / 159.f);

    float2 dv1 = *reinterpret_cast<const float2*>(d1 + (long)p * 2);
    float2 dv2 = *reinterpret_cast<const float2*>(d2 + (long)p * 2);

    int   off1[4], off2[4];
    float wgt1[4], wgt2[4];
    {
        float px = ((gx + dv1.x * (1.f / 160.f)) + 1.f) * 80.f - 0.5f;
        float py = ((gy + dv1.y * (1.f / 160.f)) + 1.f) * 80.f - 0.5f;
        float x0f = floorf(px), y0f = floorf(py);
        float wx1 = px - x0f, wy1 = py - y0f, wx0 = 1.f - wx1, wy0 = 1.f - wy1;
        int x0 = (int)x0f, y0 = (int)y0f;
        float mx0 = ((unsigned)x0       < (unsigned)W_) ? 1.f : 0.f;
        float mx1 = ((unsigned)(x0 + 1) < (unsigned)W_) ? 1.f : 0.f;
        float my0 = ((unsigned)y0       < (unsigned)H_) ? 1.f : 0.f;
        float my1 = ((unsigned)(y0 + 1) < (unsigned)H_) ? 1.f : 0.f;
        int x0c = min(max(x0, 0), W_ - 1), x1c = min(max(x0 + 1, 0), W_ - 1);
        int y0c = min(max(y0, 0), H_ - 1), y1c = min(max(y0 + 1, 0), H_ - 1);
        off1[0] = y0c * W_ + x0c; wgt1[0] = wy0 * wx0 * my0 * mx0;
        off1[1] = y0c * W_ + x1c; wgt1[1] = wy0 * wx1 * my0 * mx1;
        off1[2] = y1c * W_ + x0c; wgt1[2] = wy1 * wx0 * my1 * mx0;
        off1[3] = y1c * W_ + x1c; wgt1[3] = wy1 * wx1 * my1 * mx1;
    }
    {
        float px = ((gx + dv2.x * (1.f / 160.f)) + 1.f) * 80.f - 0.5f;
        float py = ((gy + dv2.y * (1.f / 160.f)) + 1.f) * 80.f - 0.5f;
        float x0f = floorf(px), y0f = floorf(py);
        float wx1 = px - x0f, wy1 = py - y0f, wx0 = 1.f - wx1, wy0 = 1.f - wy1;
        int x0 = (int)x0f, y0 = (int)y0f;
        float mx0 = ((unsigned)x0       < (unsigned)W_) ? 1.f : 0.f;
        float mx1 = ((unsigned)(x0 + 1) < (unsigned)W_) ? 1.f : 0.f;
        float my0 = ((unsigned)y0       < (unsigned)H_) ? 1.f : 0.f;
        float my1 = ((unsigned)(y0 + 1) < (unsigned)H_) ? 1.f : 0.f;
        int x0c = min(max(x0, 0), W_ - 1), x1c = min(max(x0 + 1, 0), W_ - 1);
        int y0c = min(max(y0, 0), H_ - 1), y1c = min(max(y0 + 1, 0), H_ - 1);
        off2[0] = y0c * W_ + x0c; wgt2[0] = wy0 * wx0 * my0 * mx0;
        off2[1] = y0c * W_ + x1c; wgt2[1] = wy0 * wx1 * my0 * mx1;
        off2[2] = y1c * W_ + x0c; wgt2[2] = wy1 * wx0 * my1 * mx0;
        off2[3] = y1c * W_ + x1c; wgt2[3] = wy1 * wx1 * my1 * mx1;
    }

    float s = 1.f + gamma[0] * imap[p];

    const float* hb = high + (long)n * 64 * HW_;
    const float* lb = low  + (long)n * 64 * HW_;
    float* fp = f + (long)n * 64 * HW_ + rem;

    ushort4 buf;
    unsigned short* bp = &buf.x;
    #pragma unroll 4
    for (int c = 0; c < 64; ++c) {
        const float* hc = hb + c * HW_;
        const float* lc = lb + c * HW_;
        float hi = hc[off1[0]] * wgt1[0] + hc[off1[1]] * wgt1[1]
                 + hc[off1[2]] * wgt1[2] + hc[off1[3]] * wgt1[3];
        float lo = lc[off2[0]] * wgt2[0] + lc[off2[1]] * wgt2[1]
                 + lc[off2[2]] * wgt2[2] + lc[off2[3]] * wgt2[3];
        float fv = (hi + lo) * s;
        fp[c * HW_] = fv;
        bp[c & 3] = f2bf(fv);
        if ((c & 3) == 3)
            *reinterpret_cast<ushort4*>(fnb + (long)p * 64 + (c - 3)) = buf;
    }
}

// -------- K5: conv3x3 pad=1, bf16 NHWC 64->1 + bias, LDS-tiled --------
__global__ __launch_bounds__(256) void out_conv_tiled(
    const unsigned short* __restrict__ fnb, const float* __restrict__ wqo,
    const float* __restrict__ ob, float* __restrict__ o)
{
    __shared__ unsigned char lds[324 * 128];
    int b  = blockIdx.x;                   // 0..799
    int n  = b / 100;
    int t  = b % 100;
    int ty = t / 10, tx = t % 10;
    int y0 = ty * 16 - 1, x0 = tx * 16 - 1;
    int tid = threadIdx.x;

    for (int i = tid; i < 324 * 8; i += 256) {
        int pix = i >> 3, qq = i & 7;
        int py = pix / 18, px = pix % 18;
        int yy = min(max(y0 + py, 0), H_ - 1);
        int xx = min(max(x0 + px, 0), W_ - 1);
        ushort8v v = *reinterpret_cast<const ushort8v*>(
            fnb + ((long)(n * HW_ + yy * W_ + xx)) * 64 + qq * 8);
        *reinterpret_cast<ushort8v*>(
            lds + ((pix * 128 + qq * 16) ^ ((pix & 7) << 4))) = v;
    }
    __syncthreads();

    int oy = tid >> 4, ox = tid & 15;
    int gy = ty * 16 + oy, gx = tx * 16 + ox;

    float acc = 0.f;
    #pragma unroll
    for (int ky = 0; ky < 3; ++ky) {
        int yy = gy + ky - 1;
        float ym = ((unsigned)yy < (unsigned)H_) ? 1.f : 0.f;
        #pragma unroll
        for (int kx = 0; kx < 3; ++kx) {
            int xx = gx + kx - 1;
            float m = (((unsigned)xx < (unsigned)W_) ? 1.f : 0.f) * ym;
            int tp = (oy + ky) * 18 + (ox + kx);
            const float* wp = wqo + (ky * 3 + kx) * 64;      // uniform
            float part = 0.f;
            #pragma unroll
            for (int qq = 0; qq < 8; ++qq) {
                ushort8v v = *reinterpret_cast<const ushort8v*>(
                    lds + ((tp * 128 + qq * 16) ^ ((tp & 7) << 4)));
                #pragma unroll
                for (int k = 0; k < 8; ++k)
                    part = fmaf(bf2f(v[k]), wp[qq * 8 + k], part);
            }
            acc = fmaf(m, part, acc);
        }
    }
    o[n * HW_ + gy * W_ + gx] = acc + ob[0];
}

extern "C" void kernel_launch(void* const* d_in, const int* in_sizes, int n_in,
                              void* d_out, int out_size, void* d_ws, size_t ws_size,
                              hipStream_t stream) {
    const float* low    = (const float*)d_in[0];
    const float* hsin   = (const float*)d_in[1];
    const float* imin   = (const float*)d_in[2];
    const float* dg1_w1 = (const float*)d_in[3];
    const float* dg1_s  = (const float*)d_in[4];
    const float* dg1_b  = (const float*)d_in[5];
    const float* dg1_m  = (const float*)d_in[6];
    const float* dg1_v  = (const float*)d_in[7];
    const float* dg1_w2 = (const float*)d_in[8];
    const float* dg2_w1 = (const float*)d_in[9];
    const float* dg2_s  = (const float*)d_in[10];
    const float* dg2_b  = (const float*)d_in[11];
    const float* dg2_m  = (const float*)d_in[12];
    const float* dg2_v  = (const float*)d_in[13];
    const float* dg2_w2 = (const float*)d_in[14];
    const float* gamma  = (const float*)d_in[15];
    const float* out_w  = (const float*)d_in[16];
    const float* out_b  = (const float*)d_in[17];

    float* ws   = (float*)d_ws;
    float* high = ws;                           // FSZ_ fp32 NCHW
    float* imap = high + FSZ_;                  // PSZ_
    float* d1   = imap + PSZ_;                  // 2*PSZ_
    float* d2   = d1 + 2 * PSZ_;                // 2*PSZ_
    float* wqd  = d2 + 2 * PSZ_;                // 2304
    float* wqo  = wqd + 2304;                   // 576
    float* beta = wqo + 576;                    // 128
    unsigned short* wqb = (unsigned short*)(beta + 128);  // 16384 bf16
    unsigned short* t1b = wqb + 16384;          // FSZ_ bf16 NHWC
    unsigned short* t2b = t1b + FSZ_;           // FSZ_ bf16 NHWC
    unsigned short* fnb = t1b;                  // aliases t1b (dead after conv3)

    float* fout = (float*)d_out;                // FSZ_ (output 0, NCHW)
    float* oout = fout + FSZ_;                  // PSZ_ (output 1)

    reorder_w_kernel<<<1, 256, 0, stream>>>(
        dg1_w1, dg2_w1, dg1_s, dg1_b, dg1_m, dg1_v,
        dg2_s, dg2_b, dg2_m, dg2_v, dg1_w2, dg2_w2, out_w,
        wqb, beta, wqd, wqo);
    resize_high_kernel<<<FSZ_ / 256, 256, 0, stream>>>(hsin, high);
    resize_imap_kernel<<<PSZ_ / 256, 256, 0, stream>>>(imin, imap);
    conv1_mfma_kernel<<<PSZ_ / 64, 256, 0, stream>>>(
        low, high, wqb, beta, t1b, t2b);
    conv3_d_tiled<<<1600, 256, 0, stream>>>(t1b, t2b, wqd, d1, d2);
    warp_combine_kernel<<<PSZ_ / 256, 256, 0, stream>>>(
        low, high, d1, d2, imap, gamma, fout, fnb);
    out_conv_tiled<<<800, 256, 0, stream>>>(fnb, wqo, out_b, oout);
}

// Round 5
// 250.892 us; speedup vs baseline: 2.6215x; 1.0867x over previous
//
#include <hip/hip_runtime.h>
#include <cmath>

#define N_   8
#define C_   64
#define H_   160
#define W_   160
#define HW_  25600
#define HH_  80
#define WH_  80
#define FSZ_ (N_ * C_ * HW_)   // 13,107,200
#define PSZ_ (N_ * HW_)        // 204,800

typedef unsigned short ushort8v __attribute__((ext_vector_type(8)));
typedef short          bf16x8  __attribute__((ext_vector_type(8)));
typedef float          f32x4   __attribute__((ext_vector_type(4)));

__device__ __forceinline__ float bf2f(unsigned short u) {
    return __uint_as_float(((unsigned)u) << 16);
}
__device__ __forceinline__ unsigned short f2bf(float f) {
    unsigned u = __float_as_uint(f);
    u += 0x7FFF + ((u >> 16) & 1);          // RNE
    return (unsigned short)(u >> 16);
}

// -------- K0: weight prep (same as R4) --------
__global__ __launch_bounds__(256) void reorder_w_kernel(
    const float* __restrict__ w1a, const float* __restrict__ w1b,
    const float* __restrict__ s1, const float* __restrict__ b1,
    const float* __restrict__ m1, const float* __restrict__ v1,
    const float* __restrict__ s2, const float* __restrict__ b2,
    const float* __restrict__ m2, const float* __restrict__ v2,
    const float* __restrict__ w2a, const float* __restrict__ w2b,
    const float* __restrict__ ow,
    unsigned short* __restrict__ wqb, float* __restrict__ beta,
    float* __restrict__ wqd, float* __restrict__ wqo)
{
    int tid = threadIdx.x;
    for (int i = tid; i < 16384; i += 256) {
        int j    = i & 7;
        int quad = (i >> 3) & 3;
        int co   = (i >> 5) & 127;
        int kb   = i >> 12;
        int k    = kb * 32 + quad * 8 + j;
        float wt, inv;
        if (co < 64) {
            wt  = w1a[co * 128 + k];
            inv = s1[co] * rsqrtf(v1[co] + 1e-5f);
        } else {
            wt  = w1b[(co - 64) * 128 + k];
            inv = s2[co - 64] * rsqrtf(v2[co - 64] + 1e-5f);
        }
        wqb[i] = f2bf(wt * inv);
    }
    for (int co = tid; co < 128; co += 256) {
        float inv, be;
        if (co < 64) {
            inv = s1[co] * rsqrtf(v1[co] + 1e-5f);
            be  = b1[co] - m1[co] * inv;
        } else {
            inv = s2[co - 64] * rsqrtf(v2[co - 64] + 1e-5f);
            be  = b2[co - 64] - m2[co - 64] * inv;
        }
        beta[co] = be;
    }
    for (int i = tid; i < 2304; i += 256) {
        int oc  = i & 1;
        int ci  = (i >> 1) & 63;
        int tap = (i >> 7) % 9;
        int br  = i / 1152;
        const float* src = br ? w2b : w2a;
        wqd[i] = src[oc * 576 + ci * 9 + tap];
    }
    for (int i = tid; i < 576; i += 256) {
        int tap = i / 64, ci = i % 64;
        wqo[i] = ow[ci * 9 + tap];
    }
}

// -------- K1: NCHW fp32 -> NHWC bf16 transpose (64 ch) --------
__global__ __launch_bounds__(256) void nchw_to_nhwc_bf16(
    const float* __restrict__ in, unsigned short* __restrict__ out, int hw)
{
    int p = blockIdx.x * 256 + threadIdx.x;   // global pixel over N*hw
    int n = p / hw, rem = p % hw;
    const float* base = in + (long)n * 64 * hw + rem;
    unsigned o32[32];
    #pragma unroll
    for (int c2 = 0; c2 < 32; ++c2) {
        float v0 = base[(long)(2 * c2) * hw];
        float v1 = base[(long)(2 * c2 + 1) * hw];
        o32[c2] = (unsigned)f2bf(v0) | ((unsigned)f2bf(v1) << 16);
    }
    uint4* dst = reinterpret_cast<uint4*>(out + (long)p * 64);
    #pragma unroll
    for (int q = 0; q < 8; ++q)
        dst[q] = make_uint4(o32[q * 4], o32[q * 4 + 1], o32[q * 4 + 2], o32[q * 4 + 3]);
}

// -------- K2: bilinear resize 80->160 (align_corners=True) in NHWC bf16 -----
__global__ __launch_bounds__(256) void resize_high_nhwc(
    const unsigned short* __restrict__ hsb, unsigned short* __restrict__ highb)
{
    int p = blockIdx.x * 256 + threadIdx.x;   // out px over N*H*W
    int n = p / HW_, rem = p % HW_;
    int y = rem / W_, x = rem % W_;
    float sx = (x * 79.0f) / 159.0f;
    float sy = (y * 79.0f) / 159.0f;
    int ix0 = (int)sx, iy0 = (int)sy;
    float fx = sx - (float)ix0, fy = sy - (float)iy0;
    int ix1 = min(ix0 + 1, WH_ - 1), iy1 = min(iy0 + 1, HH_ - 1);
    long b = (long)n * (HH_ * WH_);
    const ushort8v* r00 = (const ushort8v*)(hsb + (b + iy0 * WH_ + ix0) * 64);
    const ushort8v* r01 = (const ushort8v*)(hsb + (b + iy0 * WH_ + ix1) * 64);
    const ushort8v* r10 = (const ushort8v*)(hsb + (b + iy1 * WH_ + ix0) * 64);
    const ushort8v* r11 = (const ushort8v*)(hsb + (b + iy1 * WH_ + ix1) * 64);
    float w00 = (1.f - fx) * (1.f - fy), w01 = fx * (1.f - fy);
    float w10 = (1.f - fx) * fy,         w11 = fx * fy;

    float acc[64];
    #pragma unroll
    for (int c = 0; c < 64; ++c) acc[c] = 0.f;
    #pragma unroll
    for (int q = 0; q < 8; ++q) {
        ushort8v v0 = r00[q], v1 = r01[q], v2 = r10[q], v3 = r11[q];
        #pragma unroll
        for (int j = 0; j < 8; ++j) {
            acc[q * 8 + j] = bf2f(v0[j]) * w00 + bf2f(v1[j]) * w01
                           + bf2f(v2[j]) * w10 + bf2f(v3[j]) * w11;
        }
    }
    unsigned o32[32];
    #pragma unroll
    for (int c2 = 0; c2 < 32; ++c2)
        o32[c2] = (unsigned)f2bf(acc[2 * c2]) | ((unsigned)f2bf(acc[2 * c2 + 1]) << 16);
    uint4* dst = reinterpret_cast<uint4*>(highb + (long)p * 64);
    #pragma unroll
    for (int q = 0; q < 8; ++q)
        dst[q] = make_uint4(o32[q * 4], o32[q * 4 + 1], o32[q * 4 + 2], o32[q * 4 + 3]);
}

// -------- K1b: resize in_map 80->160 + sigmoid (fp32) --------
__global__ __launch_bounds__(256) void resize_imap_kernel(
    const float* __restrict__ im, float* __restrict__ imap)
{
    int i = blockIdx.x * 256 + threadIdx.x;
    int x = i % W_;
    int t = i / W_;
    int y = t % H_;
    int n = t / H_;
    float sx = (x * 79.0f) / 159.0f;
    float sy = (y * 79.0f) / 159.0f;
    int ix0 = (int)sx, iy0 = (int)sy;
    float fx = sx - (float)ix0, fy = sy - (float)iy0;
    int ix1 = min(ix0 + 1, WH_ - 1), iy1 = min(iy0 + 1, HH_ - 1);
    const float* p = im + n * (HH_ * WH_);
    float v00 = p[iy0 * WH_ + ix0], v01 = p[iy0 * WH_ + ix1];
    float v10 = p[iy1 * WH_ + ix0], v11 = p[iy1 * WH_ + ix1];
    float v = (v00 * (1.f - fx) + v01 * fx) * (1.f - fy)
            + (v10 * (1.f - fx) + v11 * fx) * fy;
    imap[i] = 1.f / (1.f + expf(-v));
}

// -------- K3: conv1x1 + BN via bf16 MFMA (NHWC bf16 in/out) --------
__global__ __launch_bounds__(256) void conv1_mfma_kernel(
    const unsigned short* __restrict__ lowb, const unsigned short* __restrict__ highb,
    const unsigned short* __restrict__ wqb, const float* __restrict__ beta,
    unsigned short* __restrict__ t1b, unsigned short* __restrict__ t2b)
{
    int tid  = threadIdx.x;
    int lane = tid & 63;
    int wv   = tid >> 6;
    int r16  = lane & 15;
    int quad = lane >> 4;

    int pbase = blockIdx.x * 64;
    int px_g  = pbase + wv * 16 + r16;

    const bf16x8* lr = (const bf16x8*)(lowb  + (long)px_g * 64);
    const bf16x8* hr = (const bf16x8*)(highb + (long)px_g * 64);
    bf16x8 afrag[4];
    afrag[0] = lr[quad];        // k =  0..31: ci = quad*8+j
    afrag[1] = lr[4 + quad];    // k = 32..63
    afrag[2] = hr[quad];        // k = 64..95
    afrag[3] = hr[4 + quad];    // k = 96..127

    f32x4 acc[8];
    #pragma unroll
    for (int ct = 0; ct < 8; ++ct) acc[ct] = (f32x4){0.f, 0.f, 0.f, 0.f};

    #pragma unroll
    for (int kb = 0; kb < 4; ++kb) {
        #pragma unroll
        for (int ct = 0; ct < 8; ++ct) {
            int co = ct * 16 + r16;
            bf16x8 b = *reinterpret_cast<const bf16x8*>(
                wqb + (((kb * 128 + co) * 4 + quad) << 3));
            acc[ct] = __builtin_amdgcn_mfma_f32_16x16x32_bf16(
                afrag[kb], b, acc[ct], 0, 0, 0);
        }
    }

    #pragma unroll
    for (int ct = 0; ct < 8; ++ct) {
        int co = ct * 16 + r16;
        float be = beta[co];
        unsigned short* outp = (ct < 4) ? t1b : t2b;
        int cc = co & 63;
        #pragma unroll
        for (int r = 0; r < 4; ++r) {
            int px = pbase + wv * 16 + quad * 4 + r;   // D row = (lane>>4)*4+r
            outp[(long)px * 64 + cc] = f2bf(acc[ct][r] + be);
        }
    }
}

// -------- K4: conv3x3 pad=1, bf16 NHWC 64->2, LDS-tiled --------
__global__ __launch_bounds__(256) void conv3_d_tiled(
    const unsigned short* __restrict__ t1b, const unsigned short* __restrict__ t2b,
    const float* __restrict__ wqd, float* __restrict__ d1, float* __restrict__ d2)
{
    __shared__ unsigned char lds[324 * 128];     // swizzled
    int b  = blockIdx.x;
    int br = b / 800;
    int r  = b % 800;
    int n  = r / 100;
    int t  = r % 100;
    int ty = t / 10, tx = t % 10;
    int y0 = ty * 16 - 1, x0 = tx * 16 - 1;
    int tid = threadIdx.x;

    const unsigned short* src = br ? t2b : t1b;
    float* dst = br ? d2 : d1;

    for (int i = tid; i < 324 * 8; i += 256) {
        int pix = i >> 3, qq = i & 7;
        int py = pix / 18, px = pix % 18;
        int yy = min(max(y0 + py, 0), H_ - 1);
        int xx = min(max(x0 + px, 0), W_ - 1);
        ushort8v v = *reinterpret_cast<const ushort8v*>(
            src + ((long)(n * HW_ + yy * W_ + xx)) * 64 + qq * 8);
        *reinterpret_cast<ushort8v*>(
            lds + ((pix * 128 + qq * 16) ^ ((pix & 7) << 4))) = v;
    }
    __syncthreads();

    int oy = tid >> 4, ox = tid & 15;
    int gy = ty * 16 + oy, gx = tx * 16 + ox;
    const float* wbase = wqd + br * 1152;

    float a0 = 0.f, a1 = 0.f;
    #pragma unroll
    for (int ky = 0; ky < 3; ++ky) {
        int yy = gy + ky - 1;
        float ym = ((unsigned)yy < (unsigned)H_) ? 1.f : 0.f;
        #pragma unroll
        for (int kx = 0; kx < 3; ++kx) {
            int xx = gx + kx - 1;
            float m = (((unsigned)xx < (unsigned)W_) ? 1.f : 0.f) * ym;
            int tp = (oy + ky) * 18 + (ox + kx);
            const float* wp = wbase + (ky * 3 + kx) * 128;
            float p0 = 0.f, p1 = 0.f;
            #pragma unroll
            for (int qq = 0; qq < 8; ++qq) {
                ushort8v v = *reinterpret_cast<const ushort8v*>(
                    lds + ((tp * 128 + qq * 16) ^ ((tp & 7) << 4)));
                #pragma unroll
                for (int k = 0; k < 8; ++k) {
                    float fv = bf2f(v[k]);
                    p0 = fmaf(fv, wp[(qq * 8 + k) * 2 + 0], p0);
                    p1 = fmaf(fv, wp[(qq * 8 + k) * 2 + 1], p1);
                }
            }
            a0 = fmaf(m, p0, a0);
            a1 = fmaf(m, p1, a1);
        }
    }
    int p = n * HW_ + gy * W_ + gx;
    *reinterpret_cast<float2*>(dst + (long)p * 2) = make_float2(a0, a1);
}

// -------- K5: warp+combine from NHWC bf16 -> f (fp32 NCHW) + fnb (bf16 NHWC) -
__global__ __launch_bounds__(256) void warp_combine_nhwc(
    const unsigned short* __restrict__ lowb, const unsigned short* __restrict__ highb,
    const float* __restrict__ d1, const float* __restrict__ d2,
    const float* __restrict__ imap, const float* __restrict__ gamma,
    float* __restrict__ f, unsigned short* __restrict__ fnb)
{
    int p = blockIdx.x * 256 + threadIdx.x;
    int n = p / HW_, rem = p % HW_;
    int y = rem / W_, x = rem % W_;

    float gx = -1.f + x * (2.f / 159.f);
    float gy = -1.f + y * (2.f / 159.f);

    float2 dv1 = *reinterpret_cast<const float2*>(d1 + (long)p * 2);
    float2 dv2 = *reinterpret_cast<const float2*>(d2 + (long)p * 2);

    int   idx1[4], idx2[4];
    float wgt1[4], wgt2[4];
    {
        float px = ((gx + dv1.x * (1.f / 160.f)) + 1.f) * 80.f - 0.5f;
        float py = ((gy + dv1.y * (1.f / 160.f)) + 1.f) * 80.f - 0.5f;
        float x0f = floorf(px), y0f = floorf(py);
        float wx1 = px - x0f, wy1 = py - y0f, wx0 = 1.f - wx1, wy0 = 1.f - wy1;
        int x0 = (int)x0f, y0 = (int)y0f;
        float mx0 = ((unsigned)x0       < (unsigned)W_) ? 1.f : 0.f;
        float mx1 = ((unsigned)(x0 + 1) < (unsigned)W_) ? 1.f : 0.f;
        float my0 = ((unsigned)y0       < (unsigned)H_) ? 1.f : 0.f;
        float my1 = ((unsigned)(y0 + 1) < (unsigned)H_) ? 1.f : 0.f;
        int x0c = min(max(x0, 0), W_ - 1), x1c = min(max(x0 + 1, 0), W_ - 1);
        int y0c = min(max(y0, 0), H_ - 1), y1c = min(max(y0 + 1, 0), H_ - 1);
        idx1[0] = y0c * W_ + x0c; wgt1[0] = wy0 * wx0 * my0 * mx0;
        idx1[1] = y0c * W_ + x1c; wgt1[1] = wy0 * wx1 * my0 * mx1;
        idx1[2] = y1c * W_ + x0c; wgt1[2] = wy1 * wx0 * my1 * mx0;
        idx1[3] = y1c * W_ + x1c; wgt1[3] = wy1 * wx1 * my1 * mx1;
    }
    {
        float px = ((gx + dv2.x * (1.f / 160.f)) + 1.f) * 80.f - 0.5f;
        float py = ((gy + dv2.y * (1.f / 160.f)) + 1.f) * 80.f - 0.5f;
        float x0f = floorf(px), y0f = floorf(py);
        float wx1 = px - x0f, wy1 = py - y0f, wx0 = 1.f - wx1, wy0 = 1.f - wy1;
        int x0 = (int)x0f, y0 = (int)y0f;
        float mx0 = ((unsigned)x0       < (unsigned)W_) ? 1.f : 0.f;
        float mx1 = ((unsigned)(x0 + 1) < (unsigned)W_) ? 1.f : 0.f;
        float my0 = ((unsigned)y0       < (unsigned)H_) ? 1.f : 0.f;
        float my1 = ((unsigned)(y0 + 1) < (unsigned)H_) ? 1.f : 0.f;
        int x0c = min(max(x0, 0), W_ - 1), x1c = min(max(x0 + 1, 0), W_ - 1);
        int y0c = min(max(y0, 0), H_ - 1), y1c = min(max(y0 + 1, 0), H_ - 1);
        idx2[0] = y0c * W_ + x0c; wgt2[0] = wy0 * wx0 * my0 * mx0;
        idx2[1] = y0c * W_ + x1c; wgt2[1] = wy0 * wx1 * my0 * mx1;
        idx2[2] = y1c * W_ + x0c; wgt2[2] = wy1 * wx0 * my1 * mx0;
        idx2[3] = y1c * W_ + x1c; wgt2[3] = wy1 * wx1 * my1 * mx1;
    }

    long nb = (long)n * HW_;
    float acc[64];
    #pragma unroll
    for (int c = 0; c < 64; ++c) acc[c] = 0.f;

    #pragma unroll
    for (int j = 0; j < 4; ++j) {
        const ushort8v* row = (const ushort8v*)(highb + (nb + idx1[j]) * 64);
        float w = wgt1[j];
        #pragma unroll
        for (int q = 0; q < 8; ++q) {
            ushort8v v = row[q];
            #pragma unroll
            for (int k = 0; k < 8; ++k)
                acc[q * 8 + k] = fmaf(bf2f(v[k]), w, acc[q * 8 + k]);
        }
    }
    #pragma unroll
    for (int j = 0; j < 4; ++j) {
        const ushort8v* row = (const ushort8v*)(lowb + (nb + idx2[j]) * 64);
        float w = wgt2[j];
        #pragma unroll
        for (int q = 0; q < 8; ++q) {
            ushort8v v = row[q];
            #pragma unroll
            for (int k = 0; k < 8; ++k)
                acc[q * 8 + k] = fmaf(bf2f(v[k]), w, acc[q * 8 + k]);
        }
    }

    float s = 1.f + gamma[0] * imap[p];

    float* fp = f + nb * 64 + rem;
    unsigned o32[32];
    #pragma unroll
    for (int c2 = 0; c2 < 32; ++c2) {
        float f0 = acc[2 * c2]     * s;
        float f1 = acc[2 * c2 + 1] * s;
        fp[(long)(2 * c2) * HW_]     = f0;
        fp[(long)(2 * c2 + 1) * HW_] = f1;
        o32[c2] = (unsigned)f2bf(f0) | ((unsigned)f2bf(f1) << 16);
    }
    uint4* dst = reinterpret_cast<uint4*>(fnb + (long)p * 64);
    #pragma unroll
    for (int q = 0; q < 8; ++q)
        dst[q] = make_uint4(o32[q * 4], o32[q * 4 + 1], o32[q * 4 + 2], o32[q * 4 + 3]);
}

// -------- K6: conv3x3 pad=1, bf16 NHWC 64->1 + bias, LDS-tiled --------
__global__ __launch_bounds__(256) void out_conv_tiled(
    const unsigned short* __restrict__ fnb, const float* __restrict__ wqo,
    const float* __restrict__ ob, float* __restrict__ o)
{
    __shared__ unsigned char lds[324 * 128];
    int b  = blockIdx.x;                   // 0..799
    int n  = b / 100;
    int t  = b % 100;
    int ty = t / 10, tx = t % 10;
    int y0 = ty * 16 - 1, x0 = tx * 16 - 1;
    int tid = threadIdx.x;

    for (int i = tid; i < 324 * 8; i += 256) {
        int pix = i >> 3, qq = i & 7;
        int py = pix / 18, px = pix % 18;
        int yy = min(max(y0 + py, 0), H_ - 1);
        int xx = min(max(x0 + px, 0), W_ - 1);
        ushort8v v = *reinterpret_cast<const ushort8v*>(
            fnb + ((long)(n * HW_ + yy * W_ + xx)) * 64 + qq * 8);
        *reinterpret_cast<ushort8v*>(
            lds + ((pix * 128 + qq * 16) ^ ((pix & 7) << 4))) = v;
    }
    __syncthreads();

    int oy = tid >> 4, ox = tid & 15;
    int gy = ty * 16 + oy, gx = tx * 16 + ox;

    float acc = 0.f;
    #pragma unroll
    for (int ky = 0; ky < 3; ++ky) {
        int yy = gy + ky - 1;
        float ym = ((unsigned)yy < (unsigned)H_) ? 1.f : 0.f;
        #pragma unroll
        for (int kx = 0; kx < 3; ++kx) {
            int xx = gx + kx - 1;
            float m = (((unsigned)xx < (unsigned)W_) ? 1.f : 0.f) * ym;
            int tp = (oy + ky) * 18 + (ox + kx);
            const float* wp = wqo + (ky * 3 + kx) * 64;
            float part = 0.f;
            #pragma unroll
            for (int qq = 0; qq < 8; ++qq) {
                ushort8v v = *reinterpret_cast<const ushort8v*>(
                    lds + ((tp * 128 + qq * 16) ^ ((tp & 7) << 4)));
                #pragma unroll
                for (int k = 0; k < 8; ++k)
                    part = fmaf(bf2f(v[k]), wp[qq * 8 + k], part);
            }
            acc = fmaf(m, part, acc);
        }
    }
    o[n * HW_ + gy * W_ + gx] = acc + ob[0];
}

extern "C" void kernel_launch(void* const* d_in, const int* in_sizes, int n_in,
                              void* d_out, int out_size, void* d_ws, size_t ws_size,
                              hipStream_t stream) {
    const float* low    = (const float*)d_in[0];
    const float* hsin   = (const float*)d_in[1];
    const float* imin   = (const float*)d_in[2];
    const float* dg1_w1 = (const float*)d_in[3];
    const float* dg1_s  = (const float*)d_in[4];
    const float* dg1_b  = (const float*)d_in[5];
    const float* dg1_m  = (const float*)d_in[6];
    const float* dg1_v  = (const float*)d_in[7];
    const float* dg1_w2 = (const float*)d_in[8];
    const float* dg2_w1 = (const float*)d_in[9];
    const float* dg2_s  = (const float*)d_in[10];
    const float* dg2_b  = (const float*)d_in[11];
    const float* dg2_m  = (const float*)d_in[12];
    const float* dg2_v  = (const float*)d_in[13];
    const float* dg2_w2 = (const float*)d_in[14];
    const float* gamma  = (const float*)d_in[15];
    const float* out_w  = (const float*)d_in[16];
    const float* out_b  = (const float*)d_in[17];

    float* ws   = (float*)d_ws;
    float* imap = ws;                           // PSZ_
    float* d1   = imap + PSZ_;                  // 2*PSZ_
    float* d2   = d1 + 2 * PSZ_;                // 2*PSZ_
    float* wqd  = d2 + 2 * PSZ_;                // 2304
    float* wqo  = wqd + 2304;                   // 576
    float* beta = wqo + 576;                    // 128
    unsigned short* wqb   = (unsigned short*)(beta + 128);  // 16384
    unsigned short* lowb  = wqb + 16384;        // FSZ_ bf16 NHWC
    unsigned short* highb = lowb + FSZ_;        // FSZ_ bf16 NHWC
    unsigned short* t2b   = highb + FSZ_;       // FSZ_ bf16 NHWC
    unsigned short* fnb   = t2b + FSZ_;         // FSZ_ bf16 NHWC
    unsigned short* hsb   = fnb;                // alias: hsb (3.3M shorts) dead before fnb written

    float* fout = (float*)d_out;                // FSZ_ (output 0, NCHW fp32)
    float* oout = fout + FSZ_;                  // PSZ_ (output 1)
    unsigned short* t1b = (unsigned short*)d_out;  // staged in f region; dead before warp writes f

    reorder_w_kernel<<<1, 256, 0, stream>>>(
        dg1_w1, dg2_w1, dg1_s, dg1_b, dg1_m, dg1_v,
        dg2_s, dg2_b, dg2_m, dg2_v, dg1_w2, dg2_w2, out_w,
        wqb, beta, wqd, wqo);
    nchw_to_nhwc_bf16<<<PSZ_ / 256, 256, 0, stream>>>(low, lowb, HW_);
    nchw_to_nhwc_bf16<<<(N_ * HH_ * WH_) / 256, 256, 0, stream>>>(hsin, hsb, HH_ * WH_);
    resize_high_nhwc<<<PSZ_ / 256, 256, 0, stream>>>(hsb, highb);
    resize_imap_kernel<<<PSZ_ / 256, 256, 0, stream>>>(imin, imap);
    conv1_mfma_kernel<<<PSZ_ / 64, 256, 0, stream>>>(
        lowb, highb, wqb, beta, t1b, t2b);
    conv3_d_tiled<<<1600, 256, 0, stream>>>(t1b, t2b, wqd, d1, d2);
    warp_combine_nhwc<<<PSZ_ / 256, 256, 0, stream>>>(
        lowb, highb, d1, d2, imap, gamma, fout, fnb);
    out_conv_tiled<<<800, 256, 0, stream>>>(fnb, wqo, out_b, oout);
}